// Round 4
// baseline (303.724 us; speedup 1.0000x reference)
//
#include <hip/hip_runtime.h>
#include <hip/hip_bf16.h>

// GAT layer: B=32, N=1024, IN_F=OUT_F=256, alpha=0.2
//  k1: WhT[b][o][n] = bf16(h @ W^T), MFMA; epilogue via LDS -> coalesced 128B
//      row-segment writes; fused si/sj (= Wh @ a1/a2), pre-scaled by log2(e)
//  k3: fused adj-read + masked-softmax attention + PV MFMA + ELU.
//      BARRIER-FREE: S is computed directly in MFMA A-fragment layout
//      (lane l -> row l&15, k-slice (l>>4)*8..+7), so there is no LDS round
//      trip and no __syncthreads in the whole j-loop. Each wave owns a
//      32-row x 128-col output tile and streams 32 j-steps of K=32
//      independently; adj/sj register-prefetched distance-1; whT (B-operand)
//      read straight from L2-resident global. Denominator = per-lane f32
//      accumulator + shfl_xor(16,32) reduce at the end.

#define ALPHA 0.2f
#define LOG2E 1.44269504f

typedef __bf16 bf16x8 __attribute__((ext_vector_type(8)));
typedef __bf16 bf16x4 __attribute__((ext_vector_type(4)));
typedef float  f32x4  __attribute__((ext_vector_type(4)));
typedef unsigned long long u64;

// ---------------- k1: Wh = h @ W^T -> whT (bf16) + si/sj ----------------
// grid 512 x 256 thr; block = 64 n-rows x 256 o, K chunks of 64, reg-prefetched.
__global__ __launch_bounds__(256) void k1_gemm1(const float* __restrict__ h,
                                                const float* __restrict__ W,
                                                const float* __restrict__ a_g,
                                                __bf16* __restrict__ whT,
                                                float* __restrict__ si,
                                                float* __restrict__ sj) {
    __shared__ __bf16 hA[64 * 72];
    __shared__ __bf16 hB[256 * 72];   // W tiles; reused as [o][n] out-staging
    __shared__ float  red[512];
    const int t    = threadIdx.x;
    const int r0   = blockIdx.x * 64;
    const int b    = r0 >> 10;
    const int n0   = r0 & 1023;
    const int w    = t >> 6;
    const int l    = t & 63;
    const int ln   = l & 15;
    const int quad = l >> 4;

    f32x4 acc[4][4] = {};
    float4 ha_r[4], wb_r[16];

    // preload chunk 0
    #pragma unroll
    for (int it = 0; it < 4; ++it)
        ha_r[it] = *(const float4*)&h[(size_t)(r0 + it * 16 + (t >> 4)) * 256 + (t & 15) * 4];
    #pragma unroll
    for (int it = 0; it < 16; ++it)
        wb_r[it] = *(const float4*)&W[(size_t)(it * 16 + (t >> 4)) * 256 + (t & 15) * 4];

    for (int kc = 0; kc < 4; ++kc) {
        // write staged chunk to LDS (fp32 -> bf16)
        #pragma unroll
        for (int it = 0; it < 4; ++it) {
            const float4 v = ha_r[it];
            bf16x4 pv = {(__bf16)v.x, (__bf16)v.y, (__bf16)v.z, (__bf16)v.w};
            *(bf16x4*)&hA[(it * 16 + (t >> 4)) * 72 + (t & 15) * 4] = pv;
        }
        #pragma unroll
        for (int it = 0; it < 16; ++it) {
            const float4 v = wb_r[it];
            bf16x4 pv = {(__bf16)v.x, (__bf16)v.y, (__bf16)v.z, (__bf16)v.w};
            *(bf16x4*)&hB[(it * 16 + (t >> 4)) * 72 + (t & 15) * 4] = pv;
        }
        __syncthreads();
        // prefetch next chunk while MFMA runs
        if (kc < 3) {
            const int k0 = (kc + 1) * 64;
            #pragma unroll
            for (int it = 0; it < 4; ++it)
                ha_r[it] = *(const float4*)&h[(size_t)(r0 + it * 16 + (t >> 4)) * 256 + k0 + (t & 15) * 4];
            #pragma unroll
            for (int it = 0; it < 16; ++it)
                wb_r[it] = *(const float4*)&W[(size_t)(it * 16 + (t >> 4)) * 256 + k0 + (t & 15) * 4];
        }
        #pragma unroll
        for (int kk = 0; kk < 2; ++kk) {
            bf16x8 af[4], bfr[4];
            #pragma unroll
            for (int ri = 0; ri < 4; ++ri)
                af[ri] = *(const bf16x8*)&hA[(ri * 16 + ln) * 72 + kk * 32 + quad * 8];
            #pragma unroll
            for (int oi = 0; oi < 4; ++oi)
                bfr[oi] = *(const bf16x8*)&hB[(w * 64 + oi * 16 + ln) * 72 + kk * 32 + quad * 8];
            #pragma unroll
            for (int ri = 0; ri < 4; ++ri)
                #pragma unroll
                for (int oi = 0; oi < 4; ++oi)
                    acc[ri][oi] = __builtin_amdgcn_mfma_f32_16x16x32_bf16(
                        af[ri], bfr[oi], acc[ri][oi], 0, 0, 0);
        }
        __syncthreads();
    }

    // stage acc -> hB as [o][n_local] (stride 72, conflict-light)
    #pragma unroll
    for (int ri = 0; ri < 4; ++ri) {
        const int n = ri * 16 + quad * 4;
        #pragma unroll
        for (int oi = 0; oi < 4; ++oi) {
            const int o = w * 64 + oi * 16 + ln;
            bf16x4 pv = {(__bf16)acc[ri][oi][0], (__bf16)acc[ri][oi][1],
                         (__bf16)acc[ri][oi][2], (__bf16)acc[ri][oi][3]};
            *(bf16x4*)&hB[o * 72 + n] = pv;
        }
    }
    __syncthreads();

    // whT writes: wave w covers o in [w*64, w*64+64); 8 rows x 128B per instr
    #pragma unroll
    for (int it = 0; it < 8; ++it) {
        const int o   = w * 64 + it * 8 + (l >> 3);
        const int seg = l & 7;
        const bf16x8 v = *(const bf16x8*)&hB[o * 72 + seg * 8];
        *(bf16x8*)&whT[((size_t)b * 256 + o) * 1024 + n0 + seg * 8] = v;
    }

    // fused si/sj: wave w sums o-range [w*64, w*64+64) for n = lane
    {
        float s1 = 0.f, s2 = 0.f;
        #pragma unroll 8
        for (int oi = 0; oi < 64; ++oi) {
            const int o = w * 64 + oi;
            const float v = (float)hB[o * 72 + l];
            s1 += v * a_g[o];
            s2 += v * a_g[256 + o];
        }
        red[w * 64 + l]       = s1;
        red[256 + w * 64 + l] = s2;
    }
    __syncthreads();
    // pre-scale by log2(e): leaky-relu commutes with a positive scale, so
    // k3 can use native v_exp_f32 (exp2f) directly.
    if (t < 64) {
        si[b * 1024 + n0 + t] =
            (red[t] + red[64 + t] + red[128 + t] + red[192 + t]) * LOG2E;
    } else if (t < 128) {
        const int n = t - 64;
        sj[b * 1024 + n0 + n] =
            (red[256 + n] + red[320 + n] + red[384 + n] + red[448 + n]) * LOG2E;
    }
}

// ---------------- k3: barrier-free fused attention ----------------
// grid 512 (XCD-chunked), 256 thr = 4 waves in a 2(i) x 2(o) grid.
// Wave tile: 32 rows x 128 o-cols; 32 j-steps of K=32.
// Lane l computes S for rows (l&15) and 16+(l&15), j-slice quad*8..+7 ->
// directly the MFMA A-fragment. No LDS, no barriers, no cross-lane ops
// in the loop. adj/sj prefetched distance-1 in static-named registers.

// leaky_relu(x) = max(x, ALPHA*x); masked exp2 (si/sj pre-scaled by log2e)
#define SVAL(SI, SJE, AV) \
    ({ float _e = (SI) + (SJE); _e = fmaxf(_e, ALPHA * _e); \
       (AV) > 0 ? exp2f(_e) : 0.f; })

#define K3_BODY(J, A0, A1, B0, B1, SJ0, SJ1, NA0, NA1, NB0, NB1, NSJ0, NSJ1)   \
  {                                                                            \
    const int j0 = (J) * 32;                                                   \
    /* B-fragments: whT is L2-resident; issued first, consumed after the */    \
    /* S-compute below (~250 cy of cover); counted vmcnt keeps the */          \
    /* prefetch loads in flight */                                             \
    bf16x8 bfr[8];                                                             \
    _Pragma("unroll")                                                          \
    for (int oi = 0; oi < 8; ++oi)                                             \
      bfr[oi] = *(const bf16x8*)&whTb[                                         \
          (size_t)(oc + oi * 16 + ln) * 1024 + j0 + quad * 8];                 \
    /* distance-1 prefetch of adj/sj for step J+1 */                           \
    if ((J) < 31) {                                                            \
      NA0 = *(const int4*)&adjw[(size_t)ln * 1024 + j0 + 32 + quad * 8];       \
      NA1 = *(const int4*)&adjw[(size_t)ln * 1024 + j0 + 32 + quad * 8 + 4];   \
      NB0 = *(const int4*)&adjw[(size_t)(ln + 16) * 1024 + j0 + 32 + quad * 8];\
      NB1 = *(const int4*)&adjw[(size_t)(ln + 16) * 1024 + j0 + 32 + quad * 8 + 4]; \
      NSJ0 = *(const float4*)&sj_g[bs + j0 + 32 + quad * 8];                   \
      NSJ1 = *(const float4*)&sj_g[bs + j0 + 32 + quad * 8 + 4];               \
    }                                                                          \
    /* S -> A-fragments in registers (bf16-rounded, then summed for denom) */  \
    bf16x8 af0, af1;                                                           \
    af0[0] = (__bf16)SVAL(si0, SJ0.x, A0.x);                                   \
    af0[1] = (__bf16)SVAL(si0, SJ0.y, A0.y);                                   \
    af0[2] = (__bf16)SVAL(si0, SJ0.z, A0.z);                                   \
    af0[3] = (__bf16)SVAL(si0, SJ0.w, A0.w);                                   \
    af0[4] = (__bf16)SVAL(si0, SJ1.x, A1.x);                                   \
    af0[5] = (__bf16)SVAL(si0, SJ1.y, A1.y);                                   \
    af0[6] = (__bf16)SVAL(si0, SJ1.z, A1.z);                                   \
    af0[7] = (__bf16)SVAL(si0, SJ1.w, A1.w);                                   \
    af1[0] = (__bf16)SVAL(si1, SJ0.x, B0.x);                                   \
    af1[1] = (__bf16)SVAL(si1, SJ0.y, B0.y);                                   \
    af1[2] = (__bf16)SVAL(si1, SJ0.z, B0.z);                                   \
    af1[3] = (__bf16)SVAL(si1, SJ0.w, B0.w);                                   \
    af1[4] = (__bf16)SVAL(si1, SJ1.x, B1.x);                                   \
    af1[5] = (__bf16)SVAL(si1, SJ1.y, B1.y);                                   \
    af1[6] = (__bf16)SVAL(si1, SJ1.z, B1.z);                                   \
    af1[7] = (__bf16)SVAL(si1, SJ1.w, B1.w);                                   \
    dsum0 += (float)af0[0] + (float)af0[1] + (float)af0[2] + (float)af0[3]     \
           + (float)af0[4] + (float)af0[5] + (float)af0[6] + (float)af0[7];    \
    dsum1 += (float)af1[0] + (float)af1[1] + (float)af1[2] + (float)af1[3]     \
           + (float)af1[4] + (float)af1[5] + (float)af1[6] + (float)af1[7];    \
    /* PV: 2 A-frags x 8 B-frags */                                            \
    __builtin_amdgcn_s_setprio(1);                                             \
    _Pragma("unroll")                                                          \
    for (int oi = 0; oi < 8; ++oi) {                                           \
      acc0[oi] = __builtin_amdgcn_mfma_f32_16x16x32_bf16(af0, bfr[oi],         \
                                                         acc0[oi], 0, 0, 0);   \
      acc1[oi] = __builtin_amdgcn_mfma_f32_16x16x32_bf16(af1, bfr[oi],         \
                                                         acc1[oi], 0, 0, 0);   \
    }                                                                          \
    __builtin_amdgcn_s_setprio(0);                                             \
  }

__global__ __launch_bounds__(256, 2) void k3_attn(const int* __restrict__ adj,
                                                  const __bf16* __restrict__ whT,
                                                  const float* __restrict__ si_g,
                                                  const float* __restrict__ sj_g,
                                                  float* __restrict__ out) {
    const int t = threadIdx.x;
    // XCD-chunked swizzle: 512 % 8 == 0 -> bijective; each XCD owns 64
    // consecutive wgids = 4 whole batches, so its whT slice (2 MB) stays in L2.
    const int orig = blockIdx.x;
    const int wgid = (orig & 7) * 64 + (orig >> 3);
    const int b    = wgid >> 4;
    const int i0   = (wgid & 15) << 6;
    const int w    = t >> 6;
    const int wr   = w >> 1;          // i-half: rows [wr*32, wr*32+32)
    const int oc   = (w & 1) * 128;   // o-half: cols [oc, oc+128)
    const int l    = t & 63;
    const int ln   = l & 15;
    const int quad = l >> 4;
    const int bs   = b * 1024;

    const __bf16* whTb = whT + (size_t)b * 256 * 1024;
    const int*    adjw = adj + ((size_t)(bs + i0 + wr * 32)) * 1024;

    // per-lane row scalars (si pre-scaled by log2e in k1)
    const float si0 = si_g[bs + i0 + wr * 32 + ln];
    const float si1 = si_g[bs + i0 + wr * 32 + 16 + ln];

    float dsum0 = 0.f, dsum1 = 0.f;
    f32x4 acc0[8] = {}, acc1[8] = {};

    // distance-1 prefetch registers (static names, period-2 rotation)
    int4   a0_c, a1_c, b0_c, b1_c, a0_n, a1_n, b0_n, b1_n;
    float4 sj0_c, sj1_c, sj0_n, sj1_n;
    a0_c  = *(const int4*)&adjw[(size_t)ln * 1024 + quad * 8];
    a1_c  = *(const int4*)&adjw[(size_t)ln * 1024 + quad * 8 + 4];
    b0_c  = *(const int4*)&adjw[(size_t)(ln + 16) * 1024 + quad * 8];
    b1_c  = *(const int4*)&adjw[(size_t)(ln + 16) * 1024 + quad * 8 + 4];
    sj0_c = *(const float4*)&sj_g[bs + quad * 8];
    sj1_c = *(const float4*)&sj_g[bs + quad * 8 + 4];

    for (int jj = 0; jj < 16; ++jj) {
        K3_BODY(2 * jj,     a0_c, a1_c, b0_c, b1_c, sj0_c, sj1_c,
                            a0_n, a1_n, b0_n, b1_n, sj0_n, sj1_n);
        K3_BODY(2 * jj + 1, a0_n, a1_n, b0_n, b1_n, sj0_n, sj1_n,
                            a0_c, a1_c, b0_c, b1_c, sj0_c, sj1_c);
    }

    // denominator: sum the 4 quad-partials of each row (lanes sharing ln)
    float d0 = dsum0; d0 += __shfl_xor(d0, 16); d0 += __shfl_xor(d0, 32);
    float d1 = dsum1; d1 += __shfl_xor(d1, 16); d1 += __shfl_xor(d1, 32);

    // epilogue: normalize, ELU, store.
    // C/D layout: col = ln, row(within 16) = quad*4 + q. The denominator for
    // that row lives in lane (quad*4+q) (any quad) -> shfl broadcast.
    const int rbase = bs + i0 + wr * 32;
    #pragma unroll
    for (int q = 0; q < 4; ++q) {
        const int   rloc = quad * 4 + q;
        const float inv0 = 1.0f / fmaxf(__shfl(d0, rloc), 1e-30f);
        const float inv1 = 1.0f / fmaxf(__shfl(d1, rloc), 1e-30f);
        #pragma unroll
        for (int oi = 0; oi < 8; ++oi) {
            float v0 = acc0[oi][q] * inv0;
            v0 = v0 > 0.f ? v0 : __expf(v0) - 1.f;
            out[(size_t)(rbase + rloc) * 256 + oc + oi * 16 + ln] = v0;
            float v1 = acc1[oi][q] * inv1;
            v1 = v1 > 0.f ? v1 : __expf(v1) - 1.f;
            out[(size_t)(rbase + 16 + rloc) * 256 + oc + oi * 16 + ln] = v1;
        }
    }
}

extern "C" void kernel_launch(void* const* d_in, const int* in_sizes, int n_in,
                              void* d_out, int out_size, void* d_ws, size_t ws_size,
                              hipStream_t stream) {
    const float* h   = (const float*)d_in[0];
    const int*   adj = (const int*)d_in[1];
    const float* W   = (const float*)d_in[2];
    const float* a   = (const float*)d_in[3];
    float* out = (float*)d_out;

    __bf16* whT = (__bf16*)d_ws;                              // 16 MiB
    float*  si  = (float*)((char*)d_ws + (size_t)16777216);   // 128 KiB
    float*  sj  = (float*)((char*)d_ws + (size_t)16777216 + 131072);

    k1_gemm1<<<512, 256, 0, stream>>>(h, W, a, whT, si, sj);
    k3_attn<<<512, 256, 0, stream>>>(adj, whT, si, sj, out);
}

// Round 5
// 284.991 us; speedup vs baseline: 1.0657x; 1.0657x over previous
//
#include <hip/hip_runtime.h>
#include <hip/hip_bf16.h>

// GAT layer: B=32, N=1024, IN_F=OUT_F=256, alpha=0.2
//  k0: adj (int32, 134 MB) -> TRANSPOSED bitmask maskT[b][jc][i] (u64), so k3
//      reads 16 contiguous u64 (1 cache line) per mask fetch.
//  k1: WhT[b][o][n] = bf16(h @ W^T), MFMA; fused si/sj pre-scaled by log2(e).
//  k3: fused masked-softmax attention + PV MFMA + ELU. Round-0 dataflow
//      (LDS-staged whT: coalesced full-line staging loads; S via lds_s) +
//      round-3 barrier discipline (raw s_barrier + lgkmcnt-only, counted
//      vmcnt keeps prefetch in flight across barriers; NO vmcnt(0) drain).
//      Prefetch issued at body TOP (full-body latency cover). Second bare
//      barrier closes the lds_w reuse race. setprio(1) around MFMA.

#define ALPHA 0.2f
#define LOG2E 1.44269504f

typedef __bf16 bf16x8 __attribute__((ext_vector_type(8)));
typedef __bf16 bf16x4 __attribute__((ext_vector_type(4)));
typedef float  f32x4  __attribute__((ext_vector_type(4)));
typedef unsigned long long u64;

// ---------------- k0: adj -> transposed bitmask ----------------
// word = b*16384 + jc*1024 + i ; bit j of maskT[word] = adj[b][i][jc*64+j] > 0
// 524288 words; 2048 blocks x 256 thr = 8192 waves x 64 words each.
__global__ __launch_bounds__(256) void k0_mask(const int* __restrict__ adj,
                                               u64* __restrict__ maskT) {
    const int wid = (blockIdx.x * 256 + threadIdx.x) >> 6;  // 0..8191
    const int l   = threadIdx.x & 63;
    const size_t base = (size_t)wid * 64;
    #pragma unroll 4
    for (int it = 0; it < 64; ++it) {
        const size_t word = base + it;
        const int b  = (int)(word >> 14);
        const int jc = (int)((word >> 10) & 15);
        const int i  = (int)(word & 1023);
        const int v  = adj[(((size_t)b << 10) + i) * 1024 + jc * 64 + l];
        const u64 m  = __ballot(v > 0);
        if (l == 0) maskT[word] = m;
    }
}

// ---------------- k1: Wh = h @ W^T -> whT (bf16) + si/sj ----------------
// grid 512 x 256 thr; block = 64 n-rows x 256 o, K chunks of 64, reg-prefetched.
__global__ __launch_bounds__(256) void k1_gemm1(const float* __restrict__ h,
                                                const float* __restrict__ W,
                                                const float* __restrict__ a_g,
                                                __bf16* __restrict__ whT,
                                                float* __restrict__ si,
                                                float* __restrict__ sj) {
    __shared__ __bf16 hA[64 * 72];
    __shared__ __bf16 hB[256 * 72];   // W tiles; reused as [o][n] out-staging
    __shared__ float  red[512];
    const int t    = threadIdx.x;
    const int r0   = blockIdx.x * 64;
    const int b    = r0 >> 10;
    const int n0   = r0 & 1023;
    const int w    = t >> 6;
    const int l    = t & 63;
    const int ln   = l & 15;
    const int quad = l >> 4;

    f32x4 acc[4][4] = {};
    float4 ha_r[4], wb_r[16];

    #pragma unroll
    for (int it = 0; it < 4; ++it)
        ha_r[it] = *(const float4*)&h[(size_t)(r0 + it * 16 + (t >> 4)) * 256 + (t & 15) * 4];
    #pragma unroll
    for (int it = 0; it < 16; ++it)
        wb_r[it] = *(const float4*)&W[(size_t)(it * 16 + (t >> 4)) * 256 + (t & 15) * 4];

    for (int kc = 0; kc < 4; ++kc) {
        #pragma unroll
        for (int it = 0; it < 4; ++it) {
            const float4 v = ha_r[it];
            bf16x4 pv = {(__bf16)v.x, (__bf16)v.y, (__bf16)v.z, (__bf16)v.w};
            *(bf16x4*)&hA[(it * 16 + (t >> 4)) * 72 + (t & 15) * 4] = pv;
        }
        #pragma unroll
        for (int it = 0; it < 16; ++it) {
            const float4 v = wb_r[it];
            bf16x4 pv = {(__bf16)v.x, (__bf16)v.y, (__bf16)v.z, (__bf16)v.w};
            *(bf16x4*)&hB[(it * 16 + (t >> 4)) * 72 + (t & 15) * 4] = pv;
        }
        __syncthreads();
        if (kc < 3) {
            const int k0 = (kc + 1) * 64;
            #pragma unroll
            for (int it = 0; it < 4; ++it)
                ha_r[it] = *(const float4*)&h[(size_t)(r0 + it * 16 + (t >> 4)) * 256 + k0 + (t & 15) * 4];
            #pragma unroll
            for (int it = 0; it < 16; ++it)
                wb_r[it] = *(const float4*)&W[(size_t)(it * 16 + (t >> 4)) * 256 + k0 + (t & 15) * 4];
        }
        #pragma unroll
        for (int kk = 0; kk < 2; ++kk) {
            bf16x8 af[4], bfr[4];
            #pragma unroll
            for (int ri = 0; ri < 4; ++ri)
                af[ri] = *(const bf16x8*)&hA[(ri * 16 + ln) * 72 + kk * 32 + quad * 8];
            #pragma unroll
            for (int oi = 0; oi < 4; ++oi)
                bfr[oi] = *(const bf16x8*)&hB[(w * 64 + oi * 16 + ln) * 72 + kk * 32 + quad * 8];
            #pragma unroll
            for (int ri = 0; ri < 4; ++ri)
                #pragma unroll
                for (int oi = 0; oi < 4; ++oi)
                    acc[ri][oi] = __builtin_amdgcn_mfma_f32_16x16x32_bf16(
                        af[ri], bfr[oi], acc[ri][oi], 0, 0, 0);
        }
        __syncthreads();
    }

    #pragma unroll
    for (int ri = 0; ri < 4; ++ri) {
        const int n = ri * 16 + quad * 4;
        #pragma unroll
        for (int oi = 0; oi < 4; ++oi) {
            const int o = w * 64 + oi * 16 + ln;
            bf16x4 pv = {(__bf16)acc[ri][oi][0], (__bf16)acc[ri][oi][1],
                         (__bf16)acc[ri][oi][2], (__bf16)acc[ri][oi][3]};
            *(bf16x4*)&hB[o * 72 + n] = pv;
        }
    }
    __syncthreads();

    #pragma unroll
    for (int it = 0; it < 8; ++it) {
        const int o   = w * 64 + it * 8 + (l >> 3);
        const int seg = l & 7;
        const bf16x8 v = *(const bf16x8*)&hB[o * 72 + seg * 8];
        *(bf16x8*)&whT[((size_t)b * 256 + o) * 1024 + n0 + seg * 8] = v;
    }

    {
        float s1 = 0.f, s2 = 0.f;
        #pragma unroll 8
        for (int oi = 0; oi < 64; ++oi) {
            const int o = w * 64 + oi;
            const float v = (float)hB[o * 72 + l];
            s1 += v * a_g[o];
            s2 += v * a_g[256 + o];
        }
        red[w * 64 + l]       = s1;
        red[256 + w * 64 + l] = s2;
    }
    __syncthreads();
    if (t < 64) {
        si[b * 1024 + n0 + t] =
            (red[t] + red[64 + t] + red[128 + t] + red[192 + t]) * LOG2E;
    } else if (t < 128) {
        const int n = t - 64;
        sj[b * 1024 + n0 + n] =
            (red[256 + n] + red[320 + n] + red[384 + n] + red[448 + n]) * LOG2E;
    }
}

// ---------------- k3: fused attention (LDS-staged whT + mask, drain-free) ----
// grid 512 (XCD-chunked), 256 thr (4 waves), 16 j-chunks of 64.
// Body: commit vreg->lds_w; issue prefetch(jc+1) [whT/mask/sj -> regs];
//       S(jc) from mask/sj regs -> lds_s; lgkm-barrier; MFMA (setprio);
//       bare barrier (protects lds_w/lds_s reuse). Global loads cross both
//       barriers with counted vmcnt (no drain).
#define K3_BODY(JC, MC, SJC, MN, SJN)                                          \
  {                                                                            \
    const int j0 = (JC) * 64;                                                  \
    /* commit staged whT chunk to LDS: per instr 8 rows x 128B (full lines) */ \
    _Pragma("unroll")                                                          \
    for (int it = 0; it < 8; ++it)                                             \
      *(bf16x8*)&lds_w[(it * 32 + (t >> 3)) * 72 + (t & 7) * 8] = vreg[it];    \
    /* prefetch jc+1 at body TOP: full body of latency cover (T14) */          \
    if ((JC) < 15) {                                                           \
      _Pragma("unroll")                                                        \
      for (int it = 0; it < 8; ++it)                                           \
        vreg[it] = *(const bf16x8*)&whTb[                                      \
            (size_t)(it * 32 + (t >> 3)) * 1024 + j0 + 64 + (t & 7) * 8];      \
      _Pragma("unroll")                                                        \
      for (int m = 0; m < 4; ++m)                                              \
        MN[m] = maskTb[(size_t)((JC) + 1) * 1024 + i0 + m * 16 + g];           \
      SJN = *(const float4*)&sj_g[bs + j0 + 64 + j4 * 4];                      \
    }                                                                          \
    /* S tile: w = adj ? exp2(leakyrelu(si+sj)) : 0  (si/sj pre-scaled) */     \
    _Pragma("unroll")                                                          \
    for (int m = 0; m < 4; ++m) {                                              \
      const int il = m * 16 + g;                                               \
      const unsigned bits = (unsigned)(MC[m] >> (4 * j4)) & 0xFu;              \
      float e0 = si_r[m] + SJC.x; e0 = fmaxf(e0, ALPHA * e0);                  \
      float e1 = si_r[m] + SJC.y; e1 = fmaxf(e1, ALPHA * e1);                  \
      float e2 = si_r[m] + SJC.z; e2 = fmaxf(e2, ALPHA * e2);                  \
      float e3 = si_r[m] + SJC.w; e3 = fmaxf(e3, ALPHA * e3);                  \
      const float w0 = (bits & 1u) ? exp2f(e0) : 0.f;                          \
      const float w1 = (bits & 2u) ? exp2f(e1) : 0.f;                          \
      const float w2 = (bits & 4u) ? exp2f(e2) : 0.f;                          \
      const float w3 = (bits & 8u) ? exp2f(e3) : 0.f;                          \
      bf16x4 pv = {(__bf16)w0, (__bf16)w1, (__bf16)w2, (__bf16)w3};            \
      dsum[m] += (float)pv[0] + (float)pv[1] + (float)pv[2] + (float)pv[3];    \
      *(bf16x4*)&lds_s[il * 72 + j4 * 4] = pv;                                 \
    }                                                                          \
    /* barrier 1: LDS writes visible; NO vmcnt drain (T4) */                   \
    asm volatile("s_waitcnt lgkmcnt(0)");                                      \
    __builtin_amdgcn_s_barrier();                                              \
    /* P(64x64) @ Wh(64x256) */                                                \
    __builtin_amdgcn_s_setprio(1);                                             \
    _Pragma("unroll")                                                          \
    for (int kk = 0; kk < 2; ++kk) {                                           \
      bf16x8 af[4], bfr[4];                                                    \
      _Pragma("unroll")                                                        \
      for (int ri = 0; ri < 4; ++ri)                                           \
        af[ri] = *(const bf16x8*)&lds_s[(ri * 16 + ln) * 72 + kk * 32 + quad * 8]; \
      _Pragma("unroll")                                                        \
      for (int oi = 0; oi < 4; ++oi)                                           \
        bfr[oi] = *(const bf16x8*)&lds_w[(w * 64 + oi * 16 + ln) * 72 + kk * 32 + quad * 8]; \
      _Pragma("unroll")                                                        \
      for (int ri = 0; ri < 4; ++ri)                                           \
        _Pragma("unroll")                                                      \
        for (int oi = 0; oi < 4; ++oi)                                         \
          acc[ri][oi] = __builtin_amdgcn_mfma_f32_16x16x32_bf16(               \
              af[ri], bfr[oi], acc[ri][oi], 0, 0, 0);                          \
    }                                                                          \
    __builtin_amdgcn_s_setprio(0);                                             \
    /* barrier 2: bare; this wave's ds_reads are reg-consumed (lgkm==0), so */ \
    /* next body's commit can't race lds_w/lds_s */                            \
    asm volatile("s_waitcnt lgkmcnt(0)");                                      \
    __builtin_amdgcn_s_barrier();                                              \
  }

__global__ __launch_bounds__(256, 2) void k3_attn(const u64* __restrict__ maskT,
                                                  const __bf16* __restrict__ whT,
                                                  const float* __restrict__ si_g,
                                                  const float* __restrict__ sj_g,
                                                  float* __restrict__ out) {
    __shared__ __bf16 lds_w[256 * 72];   // 36 KB whT chunk [o][j_local]
    __shared__ __bf16 lds_s[64 * 72];    // 9 KB S tile
    __shared__ float  lds_denom[64];
    const int t = threadIdx.x;
    // XCD-chunked swizzle: 512 % 8 == 0 -> bijective; each XCD owns 64
    // consecutive wgids = 4 whole batches, so its whT slice (2 MB) stays in L2.
    const int orig = blockIdx.x;
    const int wgid = (orig & 7) * 64 + (orig >> 3);
    const int b    = wgid >> 4;
    const int i0   = (wgid & 15) << 6;
    const int w    = t >> 6;
    const int l    = t & 63;
    const int ln   = l & 15;
    const int quad = l >> 4;
    const int g    = t >> 4;   // 0..15
    const int j4   = t & 15;   // 0..15
    const int bs   = b * 1024;

    float si_r[4];
    #pragma unroll
    for (int m = 0; m < 4; ++m) si_r[m] = si_g[bs + i0 + m * 16 + g];

    float dsum[4] = {0.f, 0.f, 0.f, 0.f};
    f32x4 acc[4][4] = {};
    const __bf16* whTb   = whT + (size_t)b * 256 * 1024;
    const u64*    maskTb = maskT + (size_t)b * 16384;

    // pipeline registers (static names, period-2 rotation for mask/sj)
    bf16x8 vreg[8];
    u64    m_c[4], m_n[4];
    float4 sj_c, sj_n;

    #pragma unroll
    for (int it = 0; it < 8; ++it)
        vreg[it] = *(const bf16x8*)&whTb[(size_t)(it * 32 + (t >> 3)) * 1024 + (t & 7) * 8];
    #pragma unroll
    for (int m = 0; m < 4; ++m) m_c[m] = maskTb[i0 + m * 16 + g];
    sj_c = *(const float4*)&sj_g[bs + j4 * 4];

    for (int jj = 0; jj < 8; ++jj) {
        K3_BODY(2 * jj,     m_c, sj_c, m_n, sj_n);
        K3_BODY(2 * jj + 1, m_n, sj_n, m_c, sj_c);
    }

    // reduce denominators across the 16 j4 lanes per row
    #pragma unroll
    for (int m = 0; m < 4; ++m) {
        float v = dsum[m];
        v += __shfl_xor(v, 1);
        v += __shfl_xor(v, 2);
        v += __shfl_xor(v, 4);
        v += __shfl_xor(v, 8);
        if (j4 == 0) lds_denom[m * 16 + g] = v;
    }
    __syncthreads();
    // epilogue: normalize, ELU, store
    #pragma unroll
    for (int ri = 0; ri < 4; ++ri) {
        #pragma unroll
        for (int q = 0; q < 4; ++q) {
            const int il = ri * 16 + quad * 4 + q;
            const float dinv = 1.0f / fmaxf(lds_denom[il], 1e-30f);
            #pragma unroll
            for (int oi = 0; oi < 4; ++oi) {
                const int o = w * 64 + oi * 16 + ln;
                const float v = acc[ri][oi][q] * dinv;
                const float r = v > 0.f ? v : __expf(v) - 1.f;
                out[((size_t)(bs + i0 + il)) * 256 + o] = r;
            }
        }
    }
}

extern "C" void kernel_launch(void* const* d_in, const int* in_sizes, int n_in,
                              void* d_out, int out_size, void* d_ws, size_t ws_size,
                              hipStream_t stream) {
    const float* h   = (const float*)d_in[0];
    const int*   adj = (const int*)d_in[1];
    const float* W   = (const float*)d_in[2];
    const float* a   = (const float*)d_in[3];
    float* out = (float*)d_out;

    __bf16* whT   = (__bf16*)d_ws;                                   // 16 MiB
    float*  si    = (float*)((char*)d_ws + (size_t)16777216);        // 128 KiB
    float*  sj    = (float*)((char*)d_ws + (size_t)16777216 + 131072);
    u64*    maskT = (u64*)((char*)d_ws + (size_t)16777216 + 262144); // 4 MiB

    k0_mask<<<2048, 256, 0, stream>>>(adj, maskT);
    k1_gemm1<<<512, 256, 0, stream>>>(h, W, a, whT, si, sj);
    k3_attn<<<512, 256, 0, stream>>>(maskT, whT, si, sj, out);
}

// Round 8
// 250.447 us; speedup vs baseline: 1.2127x; 1.1379x over previous
//
#include <hip/hip_runtime.h>
#include <hip/hip_bf16.h>

// GAT layer: B=32, N=1024, IN_F=OUT_F=256, alpha=0.2
//  k1: WhT[b][o][n] = bf16(h @ W^T), MFMA; fused si/sj pre-scaled by log2(e).
//  k3: fused adj-read + masked-softmax attention + PV MFMA + ELU.
//      Occupancy experiment, de-risked: 512 thr / 8 waves per block (wave w
//      owns a 32-wide o-slice; per-block staging/adj/barrier cost unchanged
//      vs the proven 4-wave r0/r5 structure) -> 2 blocks/CU = 16 waves/CU =
//      4/SIMD, double all previous variants. ALL sync via __syncthreads()
//      (proven construct; no inline-asm fences, no raw s_barrier). VGPR kept
//      ~100 (single-buffered staging) to fit __launch_bounds__(512,4) without
//      allocator pressure.

#define ALPHA 0.2f
#define LOG2E 1.44269504f

typedef __bf16 bf16x8 __attribute__((ext_vector_type(8)));
typedef __bf16 bf16x4 __attribute__((ext_vector_type(4)));
typedef float  f32x4  __attribute__((ext_vector_type(4)));
typedef unsigned long long u64;

// ---------------- k1: Wh = h @ W^T -> whT (bf16) + si/sj ----------------
// grid 512 x 256 thr; block = 64 n-rows x 256 o, K chunks of 64, reg-prefetched.
__global__ __launch_bounds__(256) void k1_gemm1(const float* __restrict__ h,
                                                const float* __restrict__ W,
                                                const float* __restrict__ a_g,
                                                __bf16* __restrict__ whT,
                                                float* __restrict__ si,
                                                float* __restrict__ sj) {
    __shared__ __bf16 hA[64 * 72];
    __shared__ __bf16 hB[256 * 72];   // W tiles; reused as [o][n] out-staging
    __shared__ float  red[512];
    const int t    = threadIdx.x;
    const int r0   = blockIdx.x * 64;
    const int b    = r0 >> 10;
    const int n0   = r0 & 1023;
    const int w    = t >> 6;
    const int l    = t & 63;
    const int ln   = l & 15;
    const int quad = l >> 4;

    f32x4 acc[4][4] = {};
    float4 ha_r[4], wb_r[16];

    #pragma unroll
    for (int it = 0; it < 4; ++it)
        ha_r[it] = *(const float4*)&h[(size_t)(r0 + it * 16 + (t >> 4)) * 256 + (t & 15) * 4];
    #pragma unroll
    for (int it = 0; it < 16; ++it)
        wb_r[it] = *(const float4*)&W[(size_t)(it * 16 + (t >> 4)) * 256 + (t & 15) * 4];

    for (int kc = 0; kc < 4; ++kc) {
        #pragma unroll
        for (int it = 0; it < 4; ++it) {
            const float4 v = ha_r[it];
            bf16x4 pv = {(__bf16)v.x, (__bf16)v.y, (__bf16)v.z, (__bf16)v.w};
            *(bf16x4*)&hA[(it * 16 + (t >> 4)) * 72 + (t & 15) * 4] = pv;
        }
        #pragma unroll
        for (int it = 0; it < 16; ++it) {
            const float4 v = wb_r[it];
            bf16x4 pv = {(__bf16)v.x, (__bf16)v.y, (__bf16)v.z, (__bf16)v.w};
            *(bf16x4*)&hB[(it * 16 + (t >> 4)) * 72 + (t & 15) * 4] = pv;
        }
        __syncthreads();
        if (kc < 3) {
            const int k0 = (kc + 1) * 64;
            #pragma unroll
            for (int it = 0; it < 4; ++it)
                ha_r[it] = *(const float4*)&h[(size_t)(r0 + it * 16 + (t >> 4)) * 256 + k0 + (t & 15) * 4];
            #pragma unroll
            for (int it = 0; it < 16; ++it)
                wb_r[it] = *(const float4*)&W[(size_t)(it * 16 + (t >> 4)) * 256 + k0 + (t & 15) * 4];
        }
        #pragma unroll
        for (int kk = 0; kk < 2; ++kk) {
            bf16x8 af[4], bfr[4];
            #pragma unroll
            for (int ri = 0; ri < 4; ++ri)
                af[ri] = *(const bf16x8*)&hA[(ri * 16 + ln) * 72 + kk * 32 + quad * 8];
            #pragma unroll
            for (int oi = 0; oi < 4; ++oi)
                bfr[oi] = *(const bf16x8*)&hB[(w * 64 + oi * 16 + ln) * 72 + kk * 32 + quad * 8];
            #pragma unroll
            for (int ri = 0; ri < 4; ++ri)
                #pragma unroll
                for (int oi = 0; oi < 4; ++oi)
                    acc[ri][oi] = __builtin_amdgcn_mfma_f32_16x16x32_bf16(
                        af[ri], bfr[oi], acc[ri][oi], 0, 0, 0);
        }
        __syncthreads();
    }

    #pragma unroll
    for (int ri = 0; ri < 4; ++ri) {
        const int n = ri * 16 + quad * 4;
        #pragma unroll
        for (int oi = 0; oi < 4; ++oi) {
            const int o = w * 64 + oi * 16 + ln;
            bf16x4 pv = {(__bf16)acc[ri][oi][0], (__bf16)acc[ri][oi][1],
                         (__bf16)acc[ri][oi][2], (__bf16)acc[ri][oi][3]};
            *(bf16x4*)&hB[o * 72 + n] = pv;
        }
    }
    __syncthreads();

    #pragma unroll
    for (int it = 0; it < 8; ++it) {
        const int o   = w * 64 + it * 8 + (l >> 3);
        const int seg = l & 7;
        const bf16x8 v = *(const bf16x8*)&hB[o * 72 + seg * 8];
        *(bf16x8*)&whT[((size_t)b * 256 + o) * 1024 + n0 + seg * 8] = v;
    }

    {
        float s1 = 0.f, s2 = 0.f;
        #pragma unroll 8
        for (int oi = 0; oi < 64; ++oi) {
            const int o = w * 64 + oi;
            const float v = (float)hB[o * 72 + l];
            s1 += v * a_g[o];
            s2 += v * a_g[256 + o];
        }
        red[w * 64 + l]       = s1;
        red[256 + w * 64 + l] = s2;
    }
    __syncthreads();
    if (t < 64) {
        si[b * 1024 + n0 + t] =
            (red[t] + red[64 + t] + red[128 + t] + red[192 + t]) * LOG2E;
    } else if (t < 128) {
        const int n = t - 64;
        sj[b * 1024 + n0 + n] =
            (red[256 + n] + red[320 + n] + red[384 + n] + red[448 + n]) * LOG2E;
    }
}

// ---------------- k3: fused attention (8 waves, __syncthreads pipeline) -----
// grid 512 (XCD-chunked), 512 thr (8 waves). 16 j-chunks of 64.
// Wave w: o-range [w*32, w*32+32). Thread t: S rows rowg=t>>4 and rowg+32,
// cols j4*4..+3. Body order (r0-proven schedule, widened):
//   commit vreg->lds_w; prefetch next whT->vreg; S->lds_s (+prefetch next
//   adj/sj into alternate regs); __syncthreads; MFMA (setprio); __syncthreads.
#define K3_BODY(JC, A0C, A1C, SJC, A0N, A1N, SJN)                              \
  {                                                                            \
    const int j0 = (JC) * 64;                                                  \
    /* commit staged whT chunk to LDS: 8 rows x 64B per instr, contiguous */   \
    _Pragma("unroll")                                                          \
    for (int it = 0; it < 4; ++it)                                             \
      *(bf16x8*)&lds_w[(it * 64 + (t >> 3)) * 72 + (t & 7) * 8] = vreg[it];    \
    /* prefetch next whT chunk (gets the S-phase as latency cover) */          \
    if ((JC) < 15) {                                                           \
      _Pragma("unroll")                                                        \
      for (int it = 0; it < 4; ++it)                                           \
        vreg[it] = *(const bf16x8*)&whTb[                                      \
            (size_t)(it * 64 + (t >> 3)) * 1024 + j0 + 64 + (t & 7) * 8];      \
      A0N = *(const int4*)&adjb[(size_t)rowg * 1024 + j0 + 64 + j4 * 4];       \
      A1N = *(const int4*)&adjb[(size_t)(rowg + 32) * 1024 + j0 + 64 + j4 * 4];\
      SJN = *(const float4*)&sj_g[bs + j0 + 64 + j4 * 4];                      \
    }                                                                          \
    /* S tile: w = adj ? exp2(leakyrelu(si+sj)) : 0  (si/sj pre-scaled) */     \
    {                                                                          \
      float e0 = si0 + SJC.x; e0 = fmaxf(e0, ALPHA * e0);                      \
      float e1 = si0 + SJC.y; e1 = fmaxf(e1, ALPHA * e1);                      \
      float e2 = si0 + SJC.z; e2 = fmaxf(e2, ALPHA * e2);                      \
      float e3 = si0 + SJC.w; e3 = fmaxf(e3, ALPHA * e3);                      \
      const float w0 = A0C.x > 0 ? exp2f(e0) : 0.f;                            \
      const float w1 = A0C.y > 0 ? exp2f(e1) : 0.f;                            \
      const float w2 = A0C.z > 0 ? exp2f(e2) : 0.f;                            \
      const float w3 = A0C.w > 0 ? exp2f(e3) : 0.f;                            \
      bf16x4 pv = {(__bf16)w0, (__bf16)w1, (__bf16)w2, (__bf16)w3};            \
      dsum0 += (float)pv[0] + (float)pv[1] + (float)pv[2] + (float)pv[3];      \
      *(bf16x4*)&lds_s[rowg * 72 + j4 * 4] = pv;                               \
    }                                                                          \
    {                                                                          \
      float e0 = si1 + SJC.x; e0 = fmaxf(e0, ALPHA * e0);                      \
      float e1 = si1 + SJC.y; e1 = fmaxf(e1, ALPHA * e1);                      \
      float e2 = si1 + SJC.z; e2 = fmaxf(e2, ALPHA * e2);                      \
      float e3 = si1 + SJC.w; e3 = fmaxf(e3, ALPHA * e3);                      \
      const float w0 = A1C.x > 0 ? exp2f(e0) : 0.f;                            \
      const float w1 = A1C.y > 0 ? exp2f(e1) : 0.f;                            \
      const float w2 = A1C.z > 0 ? exp2f(e2) : 0.f;                            \
      const float w3 = A1C.w > 0 ? exp2f(e3) : 0.f;                            \
      bf16x4 pv = {(__bf16)w0, (__bf16)w1, (__bf16)w2, (__bf16)w3};            \
      dsum1 += (float)pv[0] + (float)pv[1] + (float)pv[2] + (float)pv[3];      \
      *(bf16x4*)&lds_s[(rowg + 32) * 72 + j4 * 4] = pv;                        \
    }                                                                          \
    __syncthreads();                                                           \
    /* P(64x64) @ Wh(64x256): wave o-slice of 32 */                            \
    __builtin_amdgcn_s_setprio(1);                                             \
    _Pragma("unroll")                                                          \
    for (int kk = 0; kk < 2; ++kk) {                                           \
      bf16x8 af[4], bfr[2];                                                    \
      _Pragma("unroll")                                                        \
      for (int ri = 0; ri < 4; ++ri)                                           \
        af[ri] = *(const bf16x8*)&lds_s[(ri * 16 + ln) * 72 + kk * 32 + quad * 8]; \
      _Pragma("unroll")                                                        \
      for (int oi = 0; oi < 2; ++oi)                                           \
        bfr[oi] = *(const bf16x8*)&lds_w[(w * 32 + oi * 16 + ln) * 72 + kk * 32 + quad * 8]; \
      _Pragma("unroll")                                                        \
      for (int ri = 0; ri < 4; ++ri)                                           \
        _Pragma("unroll")                                                      \
        for (int oi = 0; oi < 2; ++oi)                                         \
          acc[ri][oi] = __builtin_amdgcn_mfma_f32_16x16x32_bf16(               \
              af[ri], bfr[oi], acc[ri][oi], 0, 0, 0);                          \
    }                                                                          \
    __builtin_amdgcn_s_setprio(0);                                             \
    __syncthreads();                                                           \
  }

__global__ __launch_bounds__(512, 4) void k3_attn(const int* __restrict__ adj,
                                                  const __bf16* __restrict__ whT,
                                                  const float* __restrict__ si_g,
                                                  const float* __restrict__ sj_g,
                                                  float* __restrict__ out) {
    __shared__ __bf16 lds_w[256 * 72];   // 36 KB whT chunk [o][j_local]
    __shared__ __bf16 lds_s[64 * 72];    // 9 KB S tile
    __shared__ float  lds_denom[64];
    const int t = threadIdx.x;           // 0..511
    // XCD-chunked swizzle: 512 % 8 == 0 -> bijective; each XCD owns 64
    // consecutive wgids = 4 whole batches, so its whT slice (2 MB) stays in L2.
    const int orig = blockIdx.x;
    const int wgid = (orig & 7) * 64 + (orig >> 3);
    const int b    = wgid >> 4;
    const int i0   = (wgid & 15) << 6;
    const int w    = t >> 6;             // 0..7
    const int l    = t & 63;
    const int ln   = l & 15;
    const int quad = l >> 4;
    const int rowg = t >> 4;             // 0..31 (S row pair: rowg, rowg+32)
    const int j4   = t & 15;             // 0..15
    const int bs   = b * 1024;

    const float si0 = si_g[bs + i0 + rowg];
    const float si1 = si_g[bs + i0 + rowg + 32];

    float dsum0 = 0.f, dsum1 = 0.f;
    f32x4 acc[4][2] = {};
    const __bf16* whTb = whT + (size_t)b * 256 * 1024;
    const int*    adjb = adj + ((size_t)(bs + i0)) * 1024;

    // staging + prefetch registers (static names, c/n rotation for adj/sj)
    bf16x8 vreg[4];
    int4   a0_c, a1_c, a0_n, a1_n;
    float4 sj_c, sj_n;

    #pragma unroll
    for (int it = 0; it < 4; ++it)
        vreg[it] = *(const bf16x8*)&whTb[(size_t)(it * 64 + (t >> 3)) * 1024 + (t & 7) * 8];
    a0_c = *(const int4*)&adjb[(size_t)rowg * 1024 + j4 * 4];
    a1_c = *(const int4*)&adjb[(size_t)(rowg + 32) * 1024 + j4 * 4];
    sj_c = *(const float4*)&sj_g[bs + j4 * 4];

    for (int jj = 0; jj < 8; ++jj) {
        K3_BODY(2 * jj,     a0_c, a1_c, sj_c, a0_n, a1_n, sj_n);
        K3_BODY(2 * jj + 1, a0_n, a1_n, sj_n, a0_c, a1_c, sj_c);
    }

    // reduce denominators across the 16 j4 lanes per row
    {
        float v = dsum0;
        v += __shfl_xor(v, 1);
        v += __shfl_xor(v, 2);
        v += __shfl_xor(v, 4);
        v += __shfl_xor(v, 8);
        if (j4 == 0) lds_denom[rowg] = v;
        float u = dsum1;
        u += __shfl_xor(u, 1);
        u += __shfl_xor(u, 2);
        u += __shfl_xor(u, 4);
        u += __shfl_xor(u, 8);
        if (j4 == 0) lds_denom[rowg + 32] = u;
    }
    __syncthreads();
    // epilogue: normalize, ELU, store
    #pragma unroll
    for (int ri = 0; ri < 4; ++ri) {
        #pragma unroll
        for (int q = 0; q < 4; ++q) {
            const int il = ri * 16 + quad * 4 + q;
            const float dinv = 1.0f / fmaxf(lds_denom[il], 1e-30f);
            #pragma unroll
            for (int oi = 0; oi < 2; ++oi) {
                const int o = w * 32 + oi * 16 + ln;
                const float v = acc[ri][oi][q] * dinv;
                const float r = v > 0.f ? v : __expf(v) - 1.f;
                out[((size_t)(bs + i0 + il)) * 256 + o] = r;
            }
        }
    }
}

extern "C" void kernel_launch(void* const* d_in, const int* in_sizes, int n_in,
                              void* d_out, int out_size, void* d_ws, size_t ws_size,
                              hipStream_t stream) {
    const float* h   = (const float*)d_in[0];
    const int*   adj = (const int*)d_in[1];
    const float* W   = (const float*)d_in[2];
    const float* a   = (const float*)d_in[3];
    float* out = (float*)d_out;

    __bf16* whT = (__bf16*)d_ws;                              // 16 MiB
    float*  si  = (float*)((char*)d_ws + (size_t)16777216);   // 128 KiB
    float*  sj  = (float*)((char*)d_ws + (size_t)16777216 + 131072);

    k1_gemm1<<<512, 256, 0, stream>>>(h, W, a, whT, si, sj);
    k3_attn<<<512, 512, 0, stream>>>(adj, whT, si, sj, out);
}